// Round 1
// baseline (862.689 us; speedup 1.0000x reference)
//
#include <hip/hip_runtime.h>
#include <math.h>

#define B_ 512
#define T_ 200
#define D_ 256
#define H_ 256

typedef unsigned int   u32;
typedef unsigned short u16;
typedef _Float16 h2 __attribute__((ext_vector_type(2)));
typedef _Float16 half8 __attribute__((ext_vector_type(8)));
typedef float f32x4 __attribute__((ext_vector_type(4)));
union U4H { uint4 u; h2 p[4]; };

__device__ __forceinline__ float sigmoid_f(float x) { return 1.0f / (1.0f + __expf(-x)); }
__device__ __forceinline__ float tanh_f(float x)    { return 1.0f - 2.0f / (__expf(2.0f * x) + 1.0f); }

#if __has_builtin(__builtin_amdgcn_fdot2)
#define FDOT2(a, b, c) __builtin_amdgcn_fdot2((a), (b), (c), false)
#else
#define FDOT2(a, b, c) fmaf((float)(a).x, (float)(b).x, fmaf((float)(a).y, (float)(b).y, (c)))
#endif

__device__ __forceinline__ u32 pack2h(float a, float b) {
    union { h2 h; u32 u; } r;
    r.h.x = (_Float16)a; r.h.y = (_Float16)b; return r.u;
}
__device__ __forceinline__ float unp(u32 u, int hi) {
    union { u32 u; _Float16 h[2]; } r; r.u = u; return (float)r.h[hi];
}

// ============================================================================
// Fragment-major f16 copy of the x-part weights (rows 0..255 of gk and ck).
// Layout: Wt[tile][kstep][lane][8] where tile = 16 output cols (0..31 gate,
// 32..47 cand), kstep = K/32, lane 0..63. Lane l holds cols tile*16+(l&15),
// k = kstep*32 + (l>>4)*8 + 0..7 — exactly one A-fragment of
// v_mfma_f32_16x16x32_f16 per dwordx4. 384 KB static, L2-resident.
// ============================================================================
__device__ __attribute__((aligned(16))) _Float16 g_Wt[48 * 8 * 64 * 8];

__global__ __launch_bounds__(512) void prep_wt(
    const float* __restrict__ gk, const float* __restrict__ ck)
{
    const int  ct   = blockIdx.x;        // 0..47
    const int  step = threadIdx.x >> 6;  // 0..7
    const int  lane = threadIdx.x & 63;
    const bool isG  = ct < 32;
    const float* W  = isG ? gk : ck;
    const int  nc   = isG ? 512 : 256;
    const int  col  = (isG ? ct : ct - 32) * 16 + (lane & 15);
    const int  k0   = step * 32 + (lane >> 4) * 8;
    half8 v;
    #pragma unroll
    for (int j = 0; j < 8; ++j)
        v[j] = (_Float16)W[(size_t)(k0 + j) * nc + col];
    *(half8*)&g_Wt[((size_t)(ct * 8 + step) * 64 + lane) * 8] = v;
}

// ============================================================================
// Projection GEMM on the matrix pipe: proj = x @ W_x (+bias) for all (b,t).
// Swapped operands: A = W-fragment (i = output col), B = x-fragment
// (j = batch row). C/D layout (HW-verified): j = lane&15, i = (lane>>4)*4+reg
// -> each lane owns 4 consecutive output cols of one batch row => identical
// packed-uint2 epilogue / pg / pc layouts as the previous fp32 kernel.
// 1600 blocks x 512 thr; 64 rows/block, all 768 cols, K=256 in registers.
// ============================================================================
__global__ __launch_bounds__(512, 2) void proj_mfma(
    const float* __restrict__ x, const float* __restrict__ gb,
    const float* __restrict__ cb,
    u32* pg,                      // aliases d_out: [102400][256] u32 (512 f16)
    u16* __restrict__ pc)         // ws: [102400][256] f16
{
    __shared__ _Float16 xs[64][264];   // +8 f16 pad: conflict-free b128 reads
    const int tid  = threadIdx.x;
    const int m0   = blockIdx.x * 64;
    const int lane = tid & 63;
    const int w    = tid >> 6;

    // ---- stage x tile fp32 -> f16 LDS (coalesced float4 loads) ----
    #pragma unroll
    for (int q = 0; q < 8; ++q) {
        int f = tid + 512 * q;
        int r = f >> 6, c = (f & 63) * 4;
        float4 v = *(const float4*)&x[(size_t)(m0 + r) * 256 + c];
        uint2 p;
        p.x = pack2h(v.x, v.y);
        p.y = pack2h(v.z, v.w);
        *(uint2*)&xs[r][c] = p;
    }
    __syncthreads();

    // ---- B-fragments for the whole block: 128 VGPRs, read once ----
    half8 xf[4][8];
    #pragma unroll
    for (int jt = 0; jt < 4; ++jt)
        #pragma unroll
        for (int kc = 0; kc < 8; ++kc)
            xf[jt][kc] = *(const half8*)&xs[jt * 16 + (lane & 15)]
                                           [kc * 32 + (lane >> 4) * 8];

    const int rsub = (lane >> 4) * 4;   // output-col sub-offset within tile
    const int mrow = m0 + (lane & 15);  // batch row (+ jt*16)

    #pragma unroll 1
    for (int p = 0; p < 6; ++p) {
        const int it = w + 8 * p;       // i-tile 0..47 (wave-uniform)
        const _Float16* ap = &g_Wt[(size_t)it * 4096];
        half8 af[8];
        #pragma unroll
        for (int kc = 0; kc < 8; ++kc)
            af[kc] = *(const half8*)&ap[(kc * 64 + lane) * 8];

        f32x4 acc[4] = {};
        #pragma unroll
        for (int kc = 0; kc < 8; ++kc)
            #pragma unroll
            for (int jt = 0; jt < 4; ++jt)
                acc[jt] = __builtin_amdgcn_mfma_f32_16x16x32_f16(
                              af[kc], xf[jt][kc], acc[jt], 0, 0, 0);

        const int n = it * 16 + rsub;   // global output col (0..767)
        if (n < 512) {                  // gate cols -> pg (f16 pairs)
            float b0 = gb[n], b1 = gb[n + 1], b2 = gb[n + 2], b3 = gb[n + 3];
            #pragma unroll
            for (int jt = 0; jt < 4; ++jt) {
                int m = mrow + jt * 16;
                uint2 v;
                v.x = pack2h(acc[jt][0] + b0, acc[jt][1] + b1);
                v.y = pack2h(acc[jt][2] + b2, acc[jt][3] + b3);
                *(uint2*)&pg[(size_t)m * 256 + (n >> 1)] = v;
            }
        } else {                        // cand cols -> pc (f16)
            int cc = n - 512;
            float b0 = cb[cc], b1 = cb[cc + 1], b2 = cb[cc + 2], b3 = cb[cc + 3];
            #pragma unroll
            for (int jt = 0; jt < 4; ++jt) {
                int m = mrow + jt * 16;
                uint2 v;
                v.x = pack2h(acc[jt][0] + b0, acc[jt][1] + b1);
                v.y = pack2h(acc[jt][2] + b2, acc[jt][3] + b3);
                *(uint2*)&pc[(size_t)m * 256 + cc] = v;
            }
        }
    }
}

// ============================================================================
// Recurrent kernel v2 (UNCHANGED, verified): register-resident f16 weights.
// 256 blocks x 512 threads, 2 batch rows/block, 2 barriers/step.
// ============================================================================
__global__ __launch_bounds__(512, 2) void gru_rec2(
    const int*   __restrict__ slen,
    const float* __restrict__ gk, const float* __restrict__ ck,
    const u32* pg,                 // aliases d_out (gate x-proj, f16 pairs)
    const u16* __restrict__ pc,    // ws (cand x-proj, f16)
    float* out)                    // aliases pg (barrier-ordered read-then-write)
{
    __shared__ _Float16 hs_h[2][256];
    __shared__ _Float16 rh_h[2][256];
    __shared__ float    uu[2][256];

    const int tid = threadIdx.x;
    const int b0  = blockIdx.x * 2;
    const int kh  = tid & 1;       // K-half (paired lanes)
    const int cA  = tid >> 1;      // reset col / cand col (0..255)
    const int cB  = cA + 256;      // update col

    // ---- one-time: recurrent weights into registers (f16 pairs along K) ----
    h2 wgA[64], wgB[64], wc[64];
    #pragma unroll
    for (int j = 0; j < 64; ++j) {
        const int k = 256 + kh * 128 + 2 * j;   // h-part rows of gk/ck
        h2 a, b, c;
        a.x = (_Float16)gk[(size_t)k * 512 + cA];
        a.y = (_Float16)gk[(size_t)(k + 1) * 512 + cA];
        b.x = (_Float16)gk[(size_t)k * 512 + cB];
        b.y = (_Float16)gk[(size_t)(k + 1) * 512 + cB];
        c.x = (_Float16)ck[(size_t)k * 256 + cA];
        c.y = (_Float16)ck[(size_t)(k + 1) * 256 + cA];
        wgA[j] = a; wgB[j] = b; wc[j] = c;
    }

    hs_h[tid >> 8][tid & 255] = (_Float16)0.0f;

    const int lenR = slen[b0 + kh];            // row handled at cand finalize
    const int colf = kh ? cB : cA;             // gate col this lane finalizes
    const int pgj  = colf >> 1;
    const int sel  = colf & 1;
    const u32* pg0 = pg + (size_t)(b0 + 0) * T_ * 256 + pgj;
    const u32* pg1 = pg + (size_t)(b0 + 1) * T_ * 256 + pgj;
    const u16* pcp = pc + (size_t)(b0 + kh) * T_ * 256 + cA;
    float*    outp = out + (size_t)(b0 + kh) * T_ * 256 + cA;

    const uint4* h4 = (const uint4*)&hs_h[0][0];  // row stride: 32 uint4
    const uint4* r4 = (const uint4*)&rh_h[0][0];

    for (int t = 0; t < T_; ++t) {
        // prefetch this step's projections (consumed after the barrier)
        const u32 pgv0 = __builtin_nontemporal_load(&pg0[(size_t)t * 256]);
        const u32 pgv1 = __builtin_nontemporal_load(&pg1[(size_t)t * 256]);
        const u16 pcv  = __builtin_nontemporal_load(&pcp[(size_t)t * 256]);

        __syncthreads();                       // A: h(t-1) writes visible

        // ---------------- gates ----------------
        float aA0 = 0.f, aA1 = 0.f, aB0 = 0.f, aB1 = 0.f;
        #pragma unroll
        for (int q = 0; q < 16; ++q) {
            U4H h0, h1;
            h0.u = h4[kh * 16 + q];            // row 0, K-window slice
            h1.u = h4[32 + kh * 16 + q];       // row 1
            #pragma unroll
            for (int j = 0; j < 4; ++j) {
                h2 w0 = wgA[4 * q + j], w1 = wgB[4 * q + j];
                aA0 = FDOT2(h0.p[j], w0, aA0);
                aA1 = FDOT2(h1.p[j], w0, aA1);
                aB0 = FDOT2(h0.p[j], w1, aB0);
                aB1 = FDOT2(h1.p[j], w1, aB1);
            }
        }
        aA0 += __shfl_xor(aA0, 1); aA1 += __shfl_xor(aA1, 1);
        aB0 += __shfl_xor(aB0, 1); aB1 += __shfl_xor(aB1, 1);

        const float pr0 = unp(pgv0, sel), pr1 = unp(pgv1, sel);
        if (kh == 0) {   // finalize reset gate for col cA -> stage r*h
            float g0 = sigmoid_f(aA0 + pr0);
            float g1 = sigmoid_f(aA1 + pr1);
            rh_h[0][cA] = (_Float16)(g0 * (float)hs_h[0][cA]);
            rh_h[1][cA] = (_Float16)(g1 * (float)hs_h[1][cA]);
        } else {         // finalize update gate for col cA
            uu[0][cA] = sigmoid_f(aB0 + pr0);
            uu[1][cA] = sigmoid_f(aB1 + pr1);
        }
        __syncthreads();                       // B: rh/uu ready

        // ---------------- candidate ----------------
        float c0 = 0.f, c1 = 0.f;
        #pragma unroll
        for (int q = 0; q < 16; ++q) {
            U4H r0, r1;
            r0.u = r4[kh * 16 + q];
            r1.u = r4[32 + kh * 16 + q];
            #pragma unroll
            for (int j = 0; j < 4; ++j) {
                h2 w = wc[4 * q + j];
                c0 = FDOT2(r0.p[j], w, c0);
                c1 = FDOT2(r1.p[j], w, c1);
            }
        }
        c0 += __shfl_xor(c0, 1); c1 += __shfl_xor(c1, 1);

        {   // lane kh finalizes batch row kh, column cA
            float csum = kh ? c1 : c0;
            float cd   = tanh_f(csum + (float)*(const _Float16*)&pcv);
            float u    = uu[kh][cA];
            float hold = (float)hs_h[kh][cA];
            float hn   = u * hold + (1.0f - u) * cd;
            bool  valid = (t < lenR);
            __builtin_nontemporal_store(valid ? hn : 0.0f, &outp[(size_t)t * 256]);
            if (valid) hs_h[kh][cA] = (_Float16)hn;
        }
    }
}

extern "C" void kernel_launch(void* const* d_in, const int* in_sizes, int n_in,
                              void* d_out, int out_size, void* d_ws, size_t ws_size,
                              hipStream_t stream) {
    const float* x    = (const float*)d_in[0];
    const int*   slen = (const int*)  d_in[1];
    const float* gk   = (const float*)d_in[2];
    const float* gb   = (const float*)d_in[3];
    const float* ck   = (const float*)d_in[4];
    const float* cb   = (const float*)d_in[5];
    float* out = (float*)d_out;
    u32*   pg  = (u32*)d_out;
    u16*   pc  = (u16*)d_ws;   // 52.4 MB cand x-proj (ws verified >= this in R2/R3)

    prep_wt<<<dim3(48), 512, 0, stream>>>(gk, ck);
    proj_mfma<<<dim3(1600), 512, 0, stream>>>(x, gb, cb, pg, pc);
    gru_rec2<<<dim3(256), 512, 0, stream>>>(slen, gk, ck, pg, pc, out);
}